// Round 5
// baseline (235.145 us; speedup 1.0000x reference)
//
#include <hip/hip_runtime.h>
#include <hip/hip_fp16.h>

// CTC loss forward, sum over batch. Linear-domain alpha recurrence with
// periodic exact power-of-2 rescaling (esum tracks the log-scale).
//
// Kernel A: compact + exponentiate emissions into fp16:
//           ws[b][t][l] = (half)exp(logp[t,b,ext[l]] + OFF)
// Kernel B: one wave per batch element; lane owns 4 consecutive trellis
//           positions; cross-lane via DPP wave_shr:1. Emission rows are
//           pipelined through a 32-deep register ring of INLINE-ASM
//           global_load_dwordx2 with manual `s_waitcnt vmcnt(31)` tied to the
//           consumed register — the compiler cannot delete or serialize this
//           pipeline (it did delete the source-level ring: R2 VGPR_Count=72).

constexpr int T = 1000, B = 32, C = 1000, S = 100;
constexpr int L = 2 * S + 1;      // 201
constexpr int RS = 204;           // padded row stride (halves), rows 408 B, 8B-aligned
constexpr int PFD = 32;           // prefetch depth (register ring)
constexpr int RROWS = T + PFD;    // 1032: covers max prefetch row index 1031
constexpr float OFF = 7.0f;       // emission log-offset: keeps per-step growth near 1.0
constexpr float LOG2E = 1.4426950408889634f;
constexpr float LN2 = 0.6931471805599453f;

// DPP wave_shr:1 — lane i reads lane i-1; lane 0 gets 0 (bound_ctrl).
__device__ __forceinline__ float dpp_shr1(float x) {
    return __int_as_float(
        __builtin_amdgcn_update_dpp(0, __float_as_int(x), 0x138, 0xF, 0xF, true));
}

// Wave-wide max of NONNEGATIVE values via gfx9 DPP ladder; result uniform (SGPR).
__device__ __forceinline__ float wave_max_nonneg(float x) {
#define DPP_MAX(ctrl)                                                        \
    x = fmaxf(x, __int_as_float(__builtin_amdgcn_update_dpp(                 \
                     0, __float_as_int(x), (ctrl), 0xF, 0xF, true)))
    DPP_MAX(0x111);  // row_shr:1
    DPP_MAX(0x112);  // row_shr:2
    DPP_MAX(0x114);  // row_shr:4
    DPP_MAX(0x118);  // row_shr:8  -> lane15/31/47/63 hold 16-lane maxes
    DPP_MAX(0x142);  // row_bcast15 -> lane31/63 hold 32-lane maxes
    DPP_MAX(0x143);  // row_bcast31 -> lane63 holds wave max
#undef DPP_MAX
    return __int_as_float(__builtin_amdgcn_readlane(__float_as_int(x), 63));
}

// 4 packed halves (as uint2, 8B) -> 4 floats
__device__ __forceinline__ void h4_to_f(const uint2 q, float& x, float& y,
                                        float& z, float& w) {
    const __half2 lo = *reinterpret_cast<const __half2*>(&q.x);
    const __half2 hi = *reinterpret_cast<const __half2*>(&q.y);
    const float2 f01 = __half22float2(lo);
    const float2 f23 = __half22float2(hi);
    x = f01.x; y = f01.y; z = f23.x; w = f23.y;
}

// ---- manual async-load pipeline primitives (compiler-opaque) ----
// Issue an 8B load; result register is NOT valid until a tied wait below.
__device__ __forceinline__ void async_ld(uint2& dst, const __half* addr) {
    asm volatile("global_load_dwordx2 %0, %1, off" : "=v"(dst) : "v"(addr));
}
// Wait until at most 31 of our loads are outstanding; ties v so its consumer
// cannot be scheduled before the wait.
__device__ __forceinline__ void wait_vm31(uint2& v) {
    asm volatile("s_waitcnt vmcnt(31)" : "+v"(v));
}
__device__ __forceinline__ void wait_vm0(uint2& v) {
    asm volatile("s_waitcnt vmcnt(0)" : "+v"(v));
}

// ---------------- Kernel A: staging ----------------
__global__ void stage_kernel(const float* __restrict__ logp,
                             const int* __restrict__ targets,
                             __half* __restrict__ ws) {
    const int t = blockIdx.x;
    const int b = blockIdx.y;
    __shared__ float row[C];
    const float* src = logp + ((size_t)t * B + b) * C;
    const int tid = threadIdx.x;
    if (tid < C / 4) {
        ((float4*)row)[tid] = ((const float4*)src)[tid];
    }
    __syncthreads();
    if (tid < RS) {
        float p;
        if (tid < L) {
            const int c = (tid & 1) ? targets[b * S + (tid >> 1)] : 0;
            p = exp2f((row[c] + OFF) * LOG2E);
        } else {
            p = 0.0f;  // pad columns 201..203 -> dead (keeps lane-50 a1..a3 == 0)
        }
        ws[((size_t)b * RROWS + t) * RS + tid] = __float2half(p);
    }
}

// ---------------- Kernel B: recurrence ----------------
__global__ void __launch_bounds__(64, 1) ctc_kernel(
        const __half* __restrict__ ws, const int* __restrict__ targets,
        const int* __restrict__ input_lens, const int* __restrict__ target_lens,
        float* __restrict__ out) {
    const int b = blockIdx.x;
    const int lane = threadIdx.x;
    // lanes 0..50 own positions 4*lane..4*lane+3; lanes 51..63 are dead (clamped col)
    const int col = (lane <= 50) ? 4 * lane : 200;
    const int Tb = input_lens[b];
    const int tl = target_lens[b];
    const __half* pw = ws + (size_t)b * RROWS * RS;

    // Skip-transition masks. Even positions are blanks -> no skip ever.
    float m1 = 0.f, m3 = 0.f;
    if (lane <= 50) {
        const int l1 = col + 1;
        if (l1 >= 3 && l1 < L) {
            const int s = (l1 - 1) >> 1;
            if (targets[b * S + s] != targets[b * S + s - 1]) m1 = 1.f;
        }
        const int l3 = col + 3;
        if (l3 >= 3 && l3 < L) {
            const int s = (l3 - 1) >> 1;
            if (targets[b * S + s] != targets[b * S + s - 1]) m3 = 1.f;
        }
    }

    // init at t=0: alpha[0] = p(blank), alpha[1] = p(tgt0), rest 0
    float a0 = 0.f, a1 = 0.f, a2 = 0.f, a3 = 0.f;
    {
        const uint2 q0 = *(const uint2*)(pw + col);
        float x, y, z, w;
        h4_to_f(q0, x, y, z, w);
        if (lane == 0) { a0 = x; a1 = y; }
    }
    int esum = 0;

#define CTC_STEP(Q_)                                  \
    do {                                              \
        float px, py, pz, pwv;                        \
        h4_to_f((Q_), px, py, pz, pwv);               \
        const float am1 = dpp_shr1(a3);               \
        const float s01 = a0 + a1;                    \
        const float s23 = a2 + a3;                    \
        const float n0 = (a0 + am1) * px;             \
        const float n1 = fmaf(am1, m1, s01) * py;     \
        const float n2 = (a1 + a2) * pz;              \
        const float n3 = fmaf(a1, m3, s23) * pwv;     \
        a0 = n0; a1 = n1; a2 = n2; a3 = n3;           \
    } while (0)

#define CTC_RESCALE()                                                          \
    do {                                                                       \
        const float mx = wave_max_nonneg(fmaxf(fmaxf(a0, a1), fmaxf(a2, a3))); \
        const unsigned bits = __float_as_uint(mx);                             \
        if (bits != 0u) {                                                      \
            const int e = (int)((bits >> 23) & 0xFFu) - 127;                   \
            const float sc = __uint_as_float((unsigned)(127 - e) << 23);       \
            a0 *= sc; a1 *= sc; a2 *= sc; a3 *= sc;                            \
            esum += e;                                                         \
        }                                                                      \
    } while (0)

    // Drain any compiler-issued loads so vmcnt counts ONLY our asm loads.
    asm volatile("s_waitcnt vmcnt(0)" ::: "memory");

    // Preload ring: P[i] <- row (1+i). After this, 32 loads outstanding.
    uint2 P[PFD];
    const __half* pf = pw + (size_t)RS + col;
#pragma unroll
    for (int i = 0; i < PFD; ++i) {
        async_ld(P[i], pf);
        pf += RS;
    }
    // pf now points at row PFD+1 (next to prefetch)

    int t = 1;
    while (t + PFD <= Tb) {
#pragma unroll
        for (int i = 0; i < PFD; ++i) {
            wait_vm31(P[i]);          // oldest load has landed
            const uint2 q = P[i];     // consume
            CTC_STEP(q);
            async_ld(P[i], pf);       // reissue: row (t+i)+PFD
            pf += RS;
            if (i == 15) CTC_RESCALE();
        }
        CTC_RESCALE();
        t += PFD;
    }
    // tail (< PFD steps): drain everything, then consume freely
    {
        const int rem = Tb - t;  // steps remaining: t..Tb-1
#pragma unroll
        for (int i = 0; i < PFD; ++i) {
            if (i < rem) {
                wait_vm0(P[i]);
                const uint2 q = P[i];
                CTC_STEP(q);
                if (i == 15) CTC_RESCALE();
            }
        }
    }
#undef CTC_STEP

    // final: sum alpha at positions 2*tl and 2*tl-1
    const int e1 = 2 * tl, e2 = 2 * tl - 1;
    float contrib = 0.f;
    if (lane <= 50) {
        if (col + 0 == e1 || col + 0 == e2) contrib += a0;
        if (col + 1 == e1 || col + 1 == e2) contrib += a1;
        if (col + 2 == e1 || col + 2 == e2) contrib += a2;
        if (col + 3 == e1 || col + 3 == e2) contrib += a3;
    }
#pragma unroll
    for (int off = 32; off; off >>= 1) contrib += __shfl_xor(contrib, off);

    if (lane == 0) {
        const float logalpha = logf(contrib) + (float)esum * LN2 - OFF * (float)Tb;
        float loss = -logalpha;
        if (!(loss < 0.5e30f)) loss = 0.f;  // zero_infinity (also catches NaN/inf)
        atomicAdd(out, loss);
    }
}

// ---------------- Fallback: direct gather (if ws too small) ----------------
__global__ void __launch_bounds__(64, 1) ctc_direct_kernel(
        const float* __restrict__ logp, const int* __restrict__ targets,
        const int* __restrict__ input_lens, const int* __restrict__ target_lens,
        float* __restrict__ out) {
    const int b = blockIdx.x;
    const int lane = threadIdx.x;
    const int col = (lane <= 50) ? 4 * lane : 200;
    const int Tb = input_lens[b];
    const int tl = target_lens[b];

    int cc[4]; float mm[4], pm[4];
#pragma unroll
    for (int i = 0; i < 4; ++i) {
        const int l = col + i;
        const bool real = (lane <= 50) && (l < L);
        pm[i] = real ? 1.f : 0.f;
        cc[i] = real ? ((l & 1) ? targets[b * S + (l >> 1)] : 0) : 0;
        float mk = 0.f;
        if (real && (l & 1) && l >= 3) {
            const int s = (l - 1) >> 1;
            if (targets[b * S + s] != targets[b * S + s - 1]) mk = 1.f;
        }
        mm[i] = mk;
    }
    const float m1 = mm[1], m3 = mm[3];

    float a0 = 0.f, a1 = 0.f, a2 = 0.f, a3 = 0.f;
    {
        const float* rowp = logp + (size_t)b * C;
        const float p0 = pm[0] * exp2f((rowp[cc[0]] + OFF) * LOG2E);
        const float p1 = pm[1] * exp2f((rowp[cc[1]] + OFF) * LOG2E);
        if (lane == 0) { a0 = p0; a1 = p1; }
    }
    int esum = 0;

    for (int t = 1; t < Tb; ++t) {
        const float* rowp = logp + ((size_t)t * B + b) * C;
        const float p0 = pm[0] * exp2f((rowp[cc[0]] + OFF) * LOG2E);
        const float p1 = pm[1] * exp2f((rowp[cc[1]] + OFF) * LOG2E);
        const float p2 = pm[2] * exp2f((rowp[cc[2]] + OFF) * LOG2E);
        const float p3 = pm[3] * exp2f((rowp[cc[3]] + OFF) * LOG2E);
        const float am1 = dpp_shr1(a3);
        const float n0 = (a0 + am1) * p0;
        const float n1 = fmaf(am1, m1, a0 + a1) * p1;
        const float n2 = (a1 + a2) * p2;
        const float n3 = fmaf(a1, m3, a2 + a3) * p3;
        a0 = n0; a1 = n1; a2 = n2; a3 = n3;
        if ((t & 15) == 0) {
            const float mx = wave_max_nonneg(fmaxf(fmaxf(a0, a1), fmaxf(a2, a3)));
            const unsigned bits = __float_as_uint(mx);
            if (bits != 0u) {
                const int e = (int)((bits >> 23) & 0xFFu) - 127;
                const float sc = __uint_as_float((unsigned)(127 - e) << 23);
                a0 *= sc; a1 *= sc; a2 *= sc; a3 *= sc;
                esum += e;
            }
        }
    }

    const int e1 = 2 * tl, e2 = 2 * tl - 1;
    float contrib = 0.f;
    if (lane <= 50) {
        if (col + 0 == e1 || col + 0 == e2) contrib += a0;
        if (col + 1 == e1 || col + 1 == e2) contrib += a1;
        if (col + 2 == e1 || col + 2 == e2) contrib += a2;
        if (col + 3 == e1 || col + 3 == e2) contrib += a3;
    }
#pragma unroll
    for (int off = 32; off; off >>= 1) contrib += __shfl_xor(contrib, off);
    if (lane == 0) {
        const float logalpha = logf(contrib) + (float)esum * LN2 - OFF * (float)Tb;
        float loss = -logalpha;
        if (!(loss < 0.5e30f)) loss = 0.f;
        atomicAdd(out, loss);
    }
}

extern "C" void kernel_launch(void* const* d_in, const int* in_sizes, int n_in,
                              void* d_out, int out_size, void* d_ws, size_t ws_size,
                              hipStream_t stream) {
    const float* logp = (const float*)d_in[0];
    const int* targets = (const int*)d_in[1];
    const int* input_lens = (const int*)d_in[2];
    const int* target_lens = (const int*)d_in[3];
    float* out = (float*)d_out;
    __half* ws = (__half*)d_ws;

    hipMemsetAsync(d_out, 0, sizeof(float), stream);

    const size_t ws_needed = (size_t)B * RROWS * RS * sizeof(__half);
    if (ws_size >= ws_needed) {
        dim3 gA(T, B);
        stage_kernel<<<gA, 256, 0, stream>>>(logp, targets, ws);
        ctc_kernel<<<B, 64, 0, stream>>>(ws, targets, input_lens, target_lens, out);
    } else {
        ctc_direct_kernel<<<B, 64, 0, stream>>>(logp, targets, input_lens, target_lens, out);
    }
}